// Round 5
// baseline (612.677 us; speedup 1.0000x reference)
//
#include <hip/hip_runtime.h>

#define B_ 1024
#define M_ 64
#define N_ 8192
#define NSG 32   // k-splits for k_G  (chunk 512 of K=16384)
#define NS3 16   // k-splits for k_H3 (chunk 512 of K=8192)

typedef __attribute__((ext_vector_type(8))) short bf16x8;
typedef __attribute__((ext_vector_type(4))) float f32x4;

__device__ inline unsigned short f2b(float f) {
    union { float f; unsigned u; } v; v.f = f;
    unsigned r = v.u + 0x7FFFu + ((v.u >> 16) & 1u);
    return (unsigned short)(r >> 16);
}
__device__ inline unsigned rne2(float lo, float hi) {
    union { float f; unsigned u; } a, b; a.f = lo; b.f = hi;
    unsigned x = (a.u + 0x7FFFu + ((a.u >> 16) & 1u)) >> 16;
    unsigned y = (b.u + 0x7FFFu + ((b.u >> 16) & 1u)) >> 16;
    return x | (y << 16);
}
__device__ inline bf16x8 cvt8(const float* p) {
    float4 f0 = *(const float4*)p;
    float4 f1 = *(const float4*)(p + 4);
    union { bf16x8 v; unsigned u[4]; } r;
    r.u[0] = rne2(f0.x, f0.y); r.u[1] = rne2(f0.z, f0.w);
    r.u[2] = rne2(f1.x, f1.y); r.u[3] = rne2(f1.z, f1.w);
    return r.v;
}
// readlane: SALU broadcast of lane l's value (l must be compile-time under unroll)
__device__ inline float rl(float v, int l) {
    return __builtin_bit_cast(float, __builtin_amdgcn_readlane(__builtin_bit_cast(int, v), l));
}

// ---------------------------------------------------------------------------
// zero the imaginary rows of out-x: out[(2b+1)*N + n] = 0
__global__ __launch_bounds__(256) void k_zero_imag(float* out) {
    int b = blockIdx.y;
    int n = (blockIdx.x * 256 + threadIdx.x) * 4;
    float4 z = make_float4(0.f, 0.f, 0.f, 0.f);
    *(float4*)(out + (size_t)(2 * b + 1) * N_ + n) = z;
}

// ---------------------------------------------------------------------------
// Abf = bf16(A) flat (2*64*8192)
__global__ __launch_bounds__(256) void k_cvtA(const float* A, unsigned short* Abf) {
    size_t i = ((size_t)blockIdx.x * 256 + threadIdx.x) * 8;
    float4 f0 = *(const float4*)(A + i);
    float4 f1 = *(const float4*)(A + i + 4);
    union { bf16x8 v; unsigned u[4]; } r;
    r.u[0] = rne2(f0.x, f0.y); r.u[1] = rne2(f0.z, f0.w);
    r.u[2] = rne2(f1.x, f1.y); r.u[3] = rne2(f1.z, f1.w);
    *(bf16x8*)(Abf + i) = r.v;
}

// ---------------------------------------------------------------------------
// WgT[o][k] bf16, o=0..127 (c_out*64+m), k=0..16383 (c_in*8192+n)
// o<64 : [ Ar[m] | -Ai[m] ] ;  o>=64 : [ Ai[m] | Ar[m] ]
__global__ __launch_bounds__(256) void k_prep_wg(const float* A, unsigned short* WgT) {
    int o = blockIdx.x;
    int kb = blockIdx.y * 2048 + threadIdx.x * 8;
    int m = o & 63;
    const float* Ar = A + (size_t)m * N_;
    const float* Ai = A + (size_t)M_ * N_ + (size_t)m * N_;
    bool oimag = o >= 64;
    bool khigh = kb >= N_;
    int koff = khigh ? kb - N_ : kb;
    const float* src = oimag ? (khigh ? Ar : Ai) : (khigh ? Ai : Ar);
    float sgn = (!oimag && khigh) ? -1.f : 1.f;
    float4 f0 = *(const float4*)(src + koff);
    float4 f1 = *(const float4*)(src + koff + 4);
    union { bf16x8 v; unsigned u[4]; } r;
    r.u[0] = rne2(sgn * f0.x, sgn * f0.y); r.u[1] = rne2(sgn * f0.z, sgn * f0.w);
    r.u[2] = rne2(sgn * f1.x, sgn * f1.y); r.u[3] = rne2(sgn * f1.z, sgn * f1.w);
    *(bf16x8*)(WgT + (size_t)o * 16384 + kb) = r.v;
}

// ---------------------------------------------------------------------------
// ATb[n][k] bf16, k = c*64+m : ATb[n][c*64+m] = A[c][m][n]
__global__ __launch_bounds__(256) void k_transpA(const float* A, unsigned short* ATb) {
    __shared__ float tile[128][65];
    int n0 = blockIdx.x * 64;
    int t = threadIdx.x;
    int nl = t % 64, r0 = t / 64;
    for (int it = 0; it < 32; ++it) {
        int row = r0 + it * 4;                       // row = c*64+m
        tile[row][nl] = A[(size_t)row * N_ + n0 + nl];
    }
    __syncthreads();
    int o = t % 128, nn0 = t / 128;
    for (int it = 0; it < 32; ++it) {
        int nn = nn0 + it * 2;
        ATb[(size_t)(n0 + nn) * 128 + o] = f2b(tile[o][nn]);
    }
}

// ---------------------------------------------------------------------------
// S = I/(rho+1e-12) + A A^H  (complex 64x64, Hermitian). fp32, unchanged.
__global__ __launch_bounds__(256) void k_Sbuild(const float* A, const float* lr,
                                                float* S, float* AAHT) {
    __shared__ float redS[8];
    int bid = blockIdx.x;
    int i = 0, rem = bid;
    while (rem >= 64 - i) { rem -= 64 - i; ++i; }
    int j = i + rem;                       // i <= j
    int t = threadIdx.x;
    const float* Ar = A;
    const float* Ai = A + (size_t)M_ * N_;
    const float* ari = Ar + (size_t)i * N_;
    const float* aii = Ai + (size_t)i * N_;
    const float* arj = Ar + (size_t)j * N_;
    const float* aij = Ai + (size_t)j * N_;
    float aR = 0.f, aI = 0.f;
#pragma unroll
    for (int it = 0; it < 8; ++it) {
        int n = it * 1024 + t * 4;
        float4 xr = *(const float4*)(ari + n);
        float4 xi = *(const float4*)(aii + n);
        float4 br = *(const float4*)(arj + n);
        float4 bi = *(const float4*)(aij + n);
        aR += xr.x * br.x + xi.x * bi.x + xr.y * br.y + xi.y * bi.y
            + xr.z * br.z + xi.z * bi.z + xr.w * br.w + xi.w * bi.w;
        aI += xi.x * br.x - xr.x * bi.x + xi.y * br.y - xr.y * bi.y
            + xi.z * br.z - xr.z * bi.z + xi.w * br.w - xr.w * bi.w;
    }
    for (int off = 32; off > 0; off >>= 1) {
        aR += __shfl_down(aR, off, 64);
        aI += __shfl_down(aI, off, 64);
    }
    int lane = t & 63, w = t >> 6;
    if (lane == 0) { redS[w * 2] = aR; redS[w * 2 + 1] = aI; }
    __syncthreads();
    if (t == 0) {
        float R = redS[0] + redS[2] + redS[4] + redS[6];
        float I = redS[1] + redS[3] + redS[5] + redS[7];
        float inv_rho = 1.0f / (expf(lr[0]) + 1e-12f);
        float diag = (i == j) ? inv_rho : 0.f;
        S[((size_t)i * 64 + j) * 2 + 0] = R + diag;
        S[((size_t)i * 64 + j) * 2 + 1] = I;
        AAHT[((size_t)j * 64 + i) * 2 + 0] = R;
        AAHT[((size_t)j * 64 + i) * 2 + 1] = I;
        if (i != j) {
            S[((size_t)j * 64 + i) * 2 + 0] = R;
            S[((size_t)j * 64 + i) * 2 + 1] = -I;
            AAHT[((size_t)i * 64 + j) * 2 + 0] = R;
            AAHT[((size_t)i * 64 + j) * 2 + 1] = -I;
        }
    }
}

// ---------------------------------------------------------------------------
// Register-resident complex Gauss-Jordan (64x64, well-conditioned, no pivoting).
// 4 waves; lane = row; wave g owns columns c = 4j+g (interleaved so dead columns
// retire evenly). Pivot COLUMN via 1 LDS write + 1 barrier; pivot ROW via
// v_readlane (SALU, no LDS pipe) — k static by full unroll.
// Wt[k][m] = (S^-1)[m][k]
__global__ __launch_bounds__(256) void k_invert(const float* S, float* Wt) {
    __shared__ float2 fvs[2][64];
    int t = threadIdx.x;
    int lane = t & 63;          // row
    int g = t >> 6;             // wave: owns columns 4j+g
    float2 m[32];
#pragma unroll
    for (int j = 0; j < 32; ++j) {
        int c = 4 * j + g;
        if (c < 64) {
            m[j] = ((const float2*)S)[(size_t)lane * 64 + c];
        } else {
            m[j] = (lane == c - 64) ? make_float2(1.f, 0.f) : make_float2(0.f, 0.f);
        }
    }
#pragma unroll
    for (int k = 0; k < 64; ++k) {
        const int par = k & 1;
        if (g == (k & 3)) fvs[par][lane] = m[k >> 2];   // publish column k (pre-update)
        __syncthreads();
        float2 f = fvs[par][lane];          // M[lane][k]
        float2 p = fvs[par][k];             // M[k][k] (broadcast read)
        float d = p.x * p.x + p.y * p.y;
        float id = 1.0f / d;
        float pix = p.x * id, piy = -p.y * id;          // 1/p
        bool isk = (lane == k);
        // unified update: m' = a*m - fp (x) srow ; lane k: a=0, fp=-pinv -> m' = pinv*srow
        float a   = isk ? 0.f : 1.f;
        float fpx = isk ? -pix : (f.x * pix - f.y * piy);
        float fpy = isk ? -piy : (f.x * piy + f.y * pix);
#pragma unroll
        for (int j = 0; j < 32; ++j) {
            if (4 * j + g > k) {            // columns <= k are dead afterwards
                float sx = rl(m[j].x, k);   // pivot-row element (pre-update, lane k)
                float sy = rl(m[j].y, k);
                m[j].x = a * m[j].x - (fpx * sx - fpy * sy);
                m[j].y = a * m[j].y - (fpx * sy + fpy * sx);
            }
        }
        // no trailing barrier: parity double-buffer; WAR separated by next barrier
    }
#pragma unroll
    for (int j = 16; j < 32; ++j) {
        int c = 4 * j + g;                  // >= 64
        ((float2*)Wt)[(size_t)(c - 64) * 64 + lane] = m[j];   // Wt[k][m=lane]
    }
}

// ---------------------------------------------------------------------------
// k_G: Gpart[split][b][o] = sum_{k in chunk} rn[b][k] * WgT[o][k]   (MFMA bf16)
__global__ __launch_bounds__(256) void k_G(const float* rn, const unsigned short* WgT,
                                           float* Gpart) {
    int t = threadIdx.x;
    int lane = t & 63;
    int w = t >> 6;
    int l15 = lane & 15;
    int q8 = (lane >> 4) * 8;
    int split = blockIdx.x;
    int b0 = blockIdx.y * 32;
    int k0 = split * 512;
    f32x4 a00 = {}, a01 = {}, a10 = {}, a11 = {};
    const float* x0 = rn + (size_t)(b0 + l15) * 16384 + k0 + q8;
    const float* x1 = x0 + (size_t)16 * 16384;
    const unsigned short* w0 = WgT + (size_t)(w * 32 + l15) * 16384 + k0 + q8;
    const unsigned short* w1 = w0 + (size_t)16 * 16384;
#pragma unroll 4
    for (int ks = 0; ks < 16; ++ks) {
        int kk = ks * 32;
        bf16x8 af0 = cvt8(x0 + kk);
        bf16x8 af1 = cvt8(x1 + kk);
        bf16x8 bf0 = *(const bf16x8*)(w0 + kk);
        bf16x8 bf1 = *(const bf16x8*)(w1 + kk);
        a00 = __builtin_amdgcn_mfma_f32_16x16x32_bf16(af0, bf0, a00, 0, 0, 0);
        a01 = __builtin_amdgcn_mfma_f32_16x16x32_bf16(af0, bf1, a01, 0, 0, 0);
        a10 = __builtin_amdgcn_mfma_f32_16x16x32_bf16(af1, bf0, a10, 0, 0, 0);
        a11 = __builtin_amdgcn_mfma_f32_16x16x32_bf16(af1, bf1, a11, 0, 0, 0);
    }
    int row = (lane >> 4) * 4;
    size_t base = (size_t)split * (B_ * 128);
    float* g00 = Gpart + base + (size_t)(b0 + row) * 128 + w * 32 + l15;
    float* g10 = Gpart + base + (size_t)(b0 + 16 + row) * 128 + w * 32 + l15;
#pragma unroll
    for (int r = 0; r < 4; ++r) {
        g00[(size_t)r * 128] = a00[r];
        g00[(size_t)r * 128 + 16] = a01[r];
        g10[(size_t)r * 128] = a10[r];
        g10[(size_t)r * 128 + 16] = a11[r];
    }
}

// ---------------------------------------------------------------------------
// per-step small: Ab = sum(Gpart) + rho*AAH*(z-u);  qb = bf16(rho*(z-u) - S^-1*Ab)
__global__ __launch_bounds__(256) void k_small12(const float* Gpart, const float* AAHT,
                                                 const float* Wt, const float* zin,
                                                 const float* uin, const float* lr,
                                                 unsigned short* qb) {
    __shared__ float2 AbS[4][64];
    int t = threadIdx.x;
    int m = t & 63;
    int w = __builtin_amdgcn_readfirstlane(t >> 6);
    int b = blockIdx.x * 4 + w;
    float rho = expf(lr[0]);
    float abR = 0.f, abI = 0.f;
    for (int k = 0; k < 64; ++k) {
        float wr = zin[(b * 2 + 0) * 64 + k] - uin[(b * 2 + 0) * 64 + k];
        float wi = zin[(b * 2 + 1) * 64 + k] - uin[(b * 2 + 1) * 64 + k];
        float2 h = *(const float2*)(AAHT + ((size_t)k * 64 + m) * 2);  // AAH[m][k]
        abR += wr * h.x - wi * h.y;
        abI += wi * h.x + wr * h.y;
    }
    float gR = 0.f, gI = 0.f;
#pragma unroll
    for (int s = 0; s < NSG; ++s) {
        gR += Gpart[(size_t)s * 131072 + (size_t)b * 128 + m];
        gI += Gpart[(size_t)s * 131072 + (size_t)b * 128 + 64 + m];
    }
    abR = gR + rho * abR;
    abI = gI + rho * abI;
    AbS[w][m] = make_float2(abR, abI);
    __syncthreads();
    float tR = 0.f, tI = 0.f;
    for (int k = 0; k < 64; ++k) {
        float2 Wv = *(const float2*)(Wt + ((size_t)k * 64 + m) * 2);   // W[m][k]
        float2 ab = AbS[w][k];
        tR += ab.x * Wv.x - ab.y * Wv.y;
        tI += ab.y * Wv.x + ab.x * Wv.y;
    }
    float wr_m = zin[(b * 2 + 0) * 64 + m] - uin[(b * 2 + 0) * 64 + m];
    float wi_m = zin[(b * 2 + 1) * 64 + m] - uin[(b * 2 + 1) * 64 + m];
    qb[(size_t)b * 128 + m] = f2b(rho * wr_m - tR);
    qb[(size_t)b * 128 + 64 + m] = f2b(rho * wi_m - tI);
}

// ---------------------------------------------------------------------------
// k_H2: x[b][n] = relu(rn_r[b][n] + sum_k qb[b][k]*ATb[n][k]), K=128 (MFMA)
__global__ __launch_bounds__(256) void k_H2(const unsigned short* qb, const unsigned short* ATb,
                                            const float* rn, float* out, unsigned short* xb) {
    int t = threadIdx.x;
    int lane = t & 63;
    int w = t >> 6;
    int l15 = lane & 15;
    int q8 = (lane >> 4) * 8;
    int b0 = blockIdx.y * 16;
    int n0 = blockIdx.x * 1024 + w * 256;
    bf16x8 a[4];
    const unsigned short* qrow = qb + (size_t)(b0 + l15) * 128 + q8;
#pragma unroll
    for (int ks = 0; ks < 4; ++ks) a[ks] = *(const bf16x8*)(qrow + ks * 32);
    int row = (lane >> 4) * 4;
#pragma unroll 2
    for (int nt = 0; nt < 16; ++nt) {
        f32x4 acc = {};
        const unsigned short* bbase = ATb + (size_t)(n0 + nt * 16 + l15) * 128 + q8;
#pragma unroll
        for (int ks = 0; ks < 4; ++ks) {
            bf16x8 bf = *(const bf16x8*)(bbase + ks * 32);
            acc = __builtin_amdgcn_mfma_f32_16x16x32_bf16(a[ks], bf, acc, 0, 0, 0);
        }
        int ncol = n0 + nt * 16 + l15;
        int brow = b0 + row;
#pragma unroll
        for (int r = 0; r < 4; ++r) {
            size_t ridx = (size_t)(brow + r) * 16384 + ncol;   // real row of rn/out
            float v = acc[r] + rn[ridx];
            v = fmaxf(v, 0.f);
            out[ridx] = v;
            xb[(size_t)(brow + r) * 8192 + ncol] = f2b(v);
        }
    }
}

// ---------------------------------------------------------------------------
// k_H3: Axpart[split][b][o] = sum_{k in chunk} xb[b][k]*Abf[o][k]  (MFMA)
__global__ __launch_bounds__(256) void k_H3(const unsigned short* xb, const unsigned short* Abf,
                                            float* Axpart) {
    int t = threadIdx.x;
    int lane = t & 63;
    int w = t >> 6;
    int l15 = lane & 15;
    int q8 = (lane >> 4) * 8;
    int split = blockIdx.x;
    int b0 = blockIdx.y * 32;
    int k0 = split * 512;
    f32x4 a00 = {}, a01 = {}, a10 = {}, a11 = {};
    const unsigned short* x0 = xb + (size_t)(b0 + l15) * 8192 + k0 + q8;
    const unsigned short* x1 = x0 + (size_t)16 * 8192;
    const unsigned short* w0 = Abf + (size_t)(w * 32 + l15) * 8192 + k0 + q8;
    const unsigned short* w1 = w0 + (size_t)16 * 8192;
#pragma unroll 4
    for (int ks = 0; ks < 16; ++ks) {
        int kk = ks * 32;
        bf16x8 af0 = *(const bf16x8*)(x0 + kk);
        bf16x8 af1 = *(const bf16x8*)(x1 + kk);
        bf16x8 bf0 = *(const bf16x8*)(w0 + kk);
        bf16x8 bf1 = *(const bf16x8*)(w1 + kk);
        a00 = __builtin_amdgcn_mfma_f32_16x16x32_bf16(af0, bf0, a00, 0, 0, 0);
        a01 = __builtin_amdgcn_mfma_f32_16x16x32_bf16(af0, bf1, a01, 0, 0, 0);
        a10 = __builtin_amdgcn_mfma_f32_16x16x32_bf16(af1, bf0, a10, 0, 0, 0);
        a11 = __builtin_amdgcn_mfma_f32_16x16x32_bf16(af1, bf1, a11, 0, 0, 0);
    }
    int row = (lane >> 4) * 4;
    size_t base = (size_t)split * (B_ * 128);
    float* g00 = Axpart + base + (size_t)(b0 + row) * 128 + w * 32 + l15;
    float* g10 = Axpart + base + (size_t)(b0 + 16 + row) * 128 + w * 32 + l15;
#pragma unroll
    for (int r = 0; r < 4; ++r) {
        g00[(size_t)r * 128] = a00[r];
        g00[(size_t)r * 128 + 16] = a01[r];
        g10[(size_t)r * 128] = a10[r];
        g10[(size_t)r * 128 + 16] = a11[r];
    }
}

// ---------------------------------------------------------------------------
// per-step epilogue
__global__ __launch_bounds__(128) void k_small3(const float* Axpart, const float* uin,
                                                const float* y, const float* le,
                                                float* z, float* u, float* uout, int last) {
    __shared__ float red[2];
    int b = blockIdx.x, t = threadIdx.x;
    size_t idx = (size_t)b * 128 + t;
    float ax = 0.f;
#pragma unroll
    for (int s = 0; s < NS3; ++s) ax += Axpart[(size_t)s * 131072 + idx];
    float uo = uin[idx], yv = y[idx];
    float v = ax + uo - yv;
    float sq = v * v;
    for (int off = 32; off > 0; off >>= 1) sq += __shfl_down(sq, off, 64);
    if ((t & 63) == 0) red[t >> 6] = sq;
    __syncthreads();
    float tot = red[0] + red[1];
    float eps = expf(le[0]);
    float scale = fminf(1.f, eps / (sqrtf(tot) + 1e-12f));
    float zv = yv + v * scale;
    float un = uo + ax - zv;
    z[idx] = zv;
    u[idx] = un;
    if (last) uout[idx] = un;
}

// ---------------------------------------------------------------------------
extern "C" void kernel_launch(void* const* d_in, const int* in_sizes, int n_in,
                              void* d_out, int out_size, void* d_ws, size_t ws_size,
                              hipStream_t stream) {
    const float* rn  = (const float*)d_in[0];   // (B,2,N)
    const float* y   = (const float*)d_in[1];   // (B,2,M)
    const float* uin = (const float*)d_in[2];   // (B,2,M)
    const float* A   = (const float*)d_in[3];   // (2,M,N)
    const float* lr  = (const float*)d_in[4];   // log_rho
    const float* le  = (const float*)d_in[5];   // log_epsilon

    float* out = (float*)d_out;
    float* ws  = (float*)d_ws;

    float* Gpart  = ws;                          // NSG*B*128      = 4,194,304 f
    float* Axpart = Gpart + (size_t)NSG * 131072;      // NS3*B*128 = 2,097,152 f
    float* S      = Axpart + (size_t)NS3 * 131072;     // 8192
    float* AAHT   = S + 8192;                    // 8192
    float* Wt     = AAHT + 8192;                 // 8192
    float* z      = Wt + 8192;                   // 131072
    float* u      = z + 131072;                  // 131072
    unsigned short* qb  = (unsigned short*)(u + 131072);   // 131072 us
    unsigned short* xb  = qb + 131072;           // B*N          = 8,388,608 us
    unsigned short* WgT = xb + (size_t)B_ * N_;  // 128*16384    = 2,097,152 us
    unsigned short* Abf = WgT + 2097152;         // 2*64*8192    = 1,048,576 us
    unsigned short* ATb = Abf + 1048576;         // 8192*128     = 1,048,576 us
    float* uout = out + (size_t)B_ * 2 * N_;

    k_zero_imag<<<dim3(8, B_), 256, 0, stream>>>(out);
    k_cvtA<<<512, 256, 0, stream>>>(A, Abf);
    k_prep_wg<<<dim3(128, 8), 256, 0, stream>>>(A, WgT);
    k_transpA<<<128, 256, 0, stream>>>(A, ATb);
    k_Sbuild<<<2080, 256, 0, stream>>>(A, lr, S, AAHT);
    k_invert<<<1, 256, 0, stream>>>(S, Wt);
    k_G<<<dim3(NSG, 32), 256, 0, stream>>>(rn, WgT, Gpart);

    for (int step = 0; step < 3; ++step) {
        const float* zp = (step == 0) ? y   : z;
        const float* up = (step == 0) ? uin : u;
        k_small12<<<256, 256, 0, stream>>>(Gpart, AAHT, Wt, zp, up, lr, qb);
        k_H2<<<dim3(8, 64), 256, 0, stream>>>(qb, ATb, rn, out, xb);
        k_H3<<<dim3(NS3, 32), 256, 0, stream>>>(xb, Abf, Axpart);
        k_small3<<<B_, 128, 0, stream>>>(Axpart, up, y, le, z, u, uout, step == 2 ? 1 : 0);
    }
}

// Round 6
// 426.041 us; speedup vs baseline: 1.4381x; 1.4381x over previous
//
#include <hip/hip_runtime.h>

#define B_ 1024
#define M_ 64
#define N_ 8192
#define NSG 32   // k-splits for k_G  (chunk 512 of K=16384)
#define NS3 16   // k-splits for k_H3 (chunk 512 of K=8192)

typedef __attribute__((ext_vector_type(8))) short bf16x8;
typedef __attribute__((ext_vector_type(4))) float f32x4;

__device__ inline unsigned short f2b(float f) {
    union { float f; unsigned u; } v; v.f = f;
    unsigned r = v.u + 0x7FFFu + ((v.u >> 16) & 1u);
    return (unsigned short)(r >> 16);
}
__device__ inline unsigned rne2(float lo, float hi) {
    union { float f; unsigned u; } a, b; a.f = lo; b.f = hi;
    unsigned x = (a.u + 0x7FFFu + ((a.u >> 16) & 1u)) >> 16;
    unsigned y = (b.u + 0x7FFFu + ((b.u >> 16) & 1u)) >> 16;
    return x | (y << 16);
}
__device__ inline bf16x8 cvt8(const float* p) {
    float4 f0 = *(const float4*)p;
    float4 f1 = *(const float4*)(p + 4);
    union { bf16x8 v; unsigned u[4]; } r;
    r.u[0] = rne2(f0.x, f0.y); r.u[1] = rne2(f0.z, f0.w);
    r.u[2] = rne2(f1.x, f1.y); r.u[3] = rne2(f1.z, f1.w);
    return r.v;
}
// readlane: broadcast of lane l's value (l compile-time under full unroll)
__device__ inline float rl(float v, int l) {
    return __builtin_bit_cast(float, __builtin_amdgcn_readlane(__builtin_bit_cast(int, v), l));
}

// ---------------------------------------------------------------------------
// zero the imaginary rows of out-x: out[(2b+1)*N + n] = 0
__global__ __launch_bounds__(256) void k_zero_imag(float* out) {
    int b = blockIdx.y;
    int n = (blockIdx.x * 256 + threadIdx.x) * 4;
    float4 z = make_float4(0.f, 0.f, 0.f, 0.f);
    *(float4*)(out + (size_t)(2 * b + 1) * N_ + n) = z;
}

// ---------------------------------------------------------------------------
// Abf = bf16(A) flat (2*64*8192)
__global__ __launch_bounds__(256) void k_cvtA(const float* A, unsigned short* Abf) {
    size_t i = ((size_t)blockIdx.x * 256 + threadIdx.x) * 8;
    float4 f0 = *(const float4*)(A + i);
    float4 f1 = *(const float4*)(A + i + 4);
    union { bf16x8 v; unsigned u[4]; } r;
    r.u[0] = rne2(f0.x, f0.y); r.u[1] = rne2(f0.z, f0.w);
    r.u[2] = rne2(f1.x, f1.y); r.u[3] = rne2(f1.z, f1.w);
    *(bf16x8*)(Abf + i) = r.v;
}

// ---------------------------------------------------------------------------
// WgT[o][k] bf16, o=0..127 (c_out*64+m), k=0..16383 (c_in*8192+n)
// o<64 : [ Ar[m] | -Ai[m] ] ;  o>=64 : [ Ai[m] | Ar[m] ]
__global__ __launch_bounds__(256) void k_prep_wg(const float* A, unsigned short* WgT) {
    int o = blockIdx.x;
    int kb = blockIdx.y * 2048 + threadIdx.x * 8;
    int m = o & 63;
    const float* Ar = A + (size_t)m * N_;
    const float* Ai = A + (size_t)M_ * N_ + (size_t)m * N_;
    bool oimag = o >= 64;
    bool khigh = kb >= N_;
    int koff = khigh ? kb - N_ : kb;
    const float* src = oimag ? (khigh ? Ar : Ai) : (khigh ? Ai : Ar);
    float sgn = (!oimag && khigh) ? -1.f : 1.f;
    float4 f0 = *(const float4*)(src + koff);
    float4 f1 = *(const float4*)(src + koff + 4);
    union { bf16x8 v; unsigned u[4]; } r;
    r.u[0] = rne2(sgn * f0.x, sgn * f0.y); r.u[1] = rne2(sgn * f0.z, sgn * f0.w);
    r.u[2] = rne2(sgn * f1.x, sgn * f1.y); r.u[3] = rne2(sgn * f1.z, sgn * f1.w);
    *(bf16x8*)(WgT + (size_t)o * 16384 + kb) = r.v;
}

// ---------------------------------------------------------------------------
// ATb[n][k] bf16, k = c*64+m : ATb[n][c*64+m] = A[c][m][n]
__global__ __launch_bounds__(256) void k_transpA(const float* A, unsigned short* ATb) {
    __shared__ float tile[128][65];
    int n0 = blockIdx.x * 64;
    int t = threadIdx.x;
    int nl = t % 64, r0 = t / 64;
    for (int it = 0; it < 32; ++it) {
        int row = r0 + it * 4;                       // row = c*64+m
        tile[row][nl] = A[(size_t)row * N_ + n0 + nl];
    }
    __syncthreads();
    int o = t % 128, nn0 = t / 128;
    for (int it = 0; it < 32; ++it) {
        int nn = nn0 + it * 2;
        ATb[(size_t)(n0 + nn) * 128 + o] = f2b(tile[o][nn]);
    }
}

// ---------------------------------------------------------------------------
// S = I/(rho+1e-12) + A A^H  (complex 64x64, Hermitian). fp32, unchanged.
__global__ __launch_bounds__(256) void k_Sbuild(const float* A, const float* lr,
                                                float* S, float* AAHT) {
    __shared__ float redS[8];
    int bid = blockIdx.x;
    int i = 0, rem = bid;
    while (rem >= 64 - i) { rem -= 64 - i; ++i; }
    int j = i + rem;                       // i <= j
    int t = threadIdx.x;
    const float* Ar = A;
    const float* Ai = A + (size_t)M_ * N_;
    const float* ari = Ar + (size_t)i * N_;
    const float* aii = Ai + (size_t)i * N_;
    const float* arj = Ar + (size_t)j * N_;
    const float* aij = Ai + (size_t)j * N_;
    float aR = 0.f, aI = 0.f;
#pragma unroll
    for (int it = 0; it < 8; ++it) {
        int n = it * 1024 + t * 4;
        float4 xr = *(const float4*)(ari + n);
        float4 xi = *(const float4*)(aii + n);
        float4 br = *(const float4*)(arj + n);
        float4 bi = *(const float4*)(aij + n);
        aR += xr.x * br.x + xi.x * bi.x + xr.y * br.y + xi.y * bi.y
            + xr.z * br.z + xi.z * bi.z + xr.w * br.w + xi.w * bi.w;
        aI += xi.x * br.x - xr.x * bi.x + xi.y * br.y - xr.y * bi.y
            + xi.z * br.z - xr.z * bi.z + xi.w * br.w - xr.w * bi.w;
    }
    for (int off = 32; off > 0; off >>= 1) {
        aR += __shfl_down(aR, off, 64);
        aI += __shfl_down(aI, off, 64);
    }
    int lane = t & 63, w = t >> 6;
    if (lane == 0) { redS[w * 2] = aR; redS[w * 2 + 1] = aI; }
    __syncthreads();
    if (t == 0) {
        float R = redS[0] + redS[2] + redS[4] + redS[6];
        float I = redS[1] + redS[3] + redS[5] + redS[7];
        float inv_rho = 1.0f / (expf(lr[0]) + 1e-12f);
        float diag = (i == j) ? inv_rho : 0.f;
        S[((size_t)i * 64 + j) * 2 + 0] = R + diag;
        S[((size_t)i * 64 + j) * 2 + 1] = I;
        AAHT[((size_t)j * 64 + i) * 2 + 0] = R;
        AAHT[((size_t)j * 64 + i) * 2 + 1] = I;
        if (i != j) {
            S[((size_t)j * 64 + i) * 2 + 0] = R;
            S[((size_t)j * 64 + i) * 2 + 1] = -I;
            AAHT[((size_t)i * 64 + j) * 2 + 0] = R;
            AAHT[((size_t)i * 64 + j) * 2 + 1] = -I;
        }
    }
}

// ---------------------------------------------------------------------------
// Register-resident complex Gauss-Jordan (64x64, well-conditioned, no pivoting).
// 8 waves; lane = row; wave g owns columns c = 8j+g (j<16) -> m[16] = 32 VGPRs.
// __launch_bounds__(512,2) caps at 256 VGPR/wave: NO spill (r5 failure: default
// occupancy target capped VGPRs at 64 and spilled the matrix to scratch ->
// 216us of serialized L2 round-trips).
// Pivot column via 1 LDS write + 1 barrier (parity dbuf); pivot row via
// v_readlane (static k under full unroll). Wt[k][m] = (S^-1)[m][k]
__global__ __launch_bounds__(512, 2) void k_invert(const float* S, float* Wt) {
    __shared__ float2 fvs[2][64];
    int t = threadIdx.x;
    int lane = t & 63;          // row
    int g = t >> 6;             // wave: owns columns 8j+g
    float2 m[16];
#pragma unroll
    for (int j = 0; j < 16; ++j) {
        int c = 8 * j + g;
        if (c < 64) {
            m[j] = ((const float2*)S)[(size_t)lane * 64 + c];
        } else {
            m[j] = (lane == c - 64) ? make_float2(1.f, 0.f) : make_float2(0.f, 0.f);
        }
    }
#pragma unroll
    for (int k = 0; k < 64; ++k) {
        const int par = k & 1;
        if (g == (k & 7)) fvs[par][lane] = m[k >> 3];   // publish column k (pre-update)
        __syncthreads();
        float2 f = fvs[par][lane];          // M[lane][k]
        float2 p = fvs[par][k];             // M[k][k] (broadcast read)
        float d = p.x * p.x + p.y * p.y;
        float id = 1.0f / d;
        float pix = p.x * id, piy = -p.y * id;          // 1/p
        bool isk = (lane == k);
        // unified update: m' = a*m - fp (x) srow ; lane k: a=0, fp=-pinv -> m' = pinv*srow
        float a   = isk ? 0.f : 1.f;
        float fpx = isk ? -pix : (f.x * pix - f.y * piy);
        float fpy = isk ? -piy : (f.x * piy + f.y * pix);
#pragma unroll
        for (int j = 0; j < 16; ++j) {
            if (8 * j + g > k) {            // columns <= k are dead afterwards
                float sx = rl(m[j].x, k);   // pivot-row element (pre-update, lane k)
                float sy = rl(m[j].y, k);
                m[j].x = a * m[j].x - (fpx * sx - fpy * sy);
                m[j].y = a * m[j].y - (fpx * sy + fpy * sx);
            }
        }
        // no trailing barrier: parity double-buffer; WAR separated by next barrier
    }
#pragma unroll
    for (int j = 8; j < 16; ++j) {
        int c = 8 * j + g;                  // >= 64
        ((float2*)Wt)[(size_t)(c - 64) * 64 + lane] = m[j];   // Wt[k][m=lane]
    }
}

// ---------------------------------------------------------------------------
// k_G: Gpart[split][b][o] = sum_{k in chunk} rn[b][k] * WgT[o][k]   (MFMA bf16)
__global__ __launch_bounds__(256) void k_G(const float* rn, const unsigned short* WgT,
                                           float* Gpart) {
    int t = threadIdx.x;
    int lane = t & 63;
    int w = t >> 6;
    int l15 = lane & 15;
    int q8 = (lane >> 4) * 8;
    int split = blockIdx.x;
    int b0 = blockIdx.y * 32;
    int k0 = split * 512;
    f32x4 a00 = {}, a01 = {}, a10 = {}, a11 = {};
    const float* x0 = rn + (size_t)(b0 + l15) * 16384 + k0 + q8;
    const float* x1 = x0 + (size_t)16 * 16384;
    const unsigned short* w0 = WgT + (size_t)(w * 32 + l15) * 16384 + k0 + q8;
    const unsigned short* w1 = w0 + (size_t)16 * 16384;
#pragma unroll 4
    for (int ks = 0; ks < 16; ++ks) {
        int kk = ks * 32;
        bf16x8 af0 = cvt8(x0 + kk);
        bf16x8 af1 = cvt8(x1 + kk);
        bf16x8 bf0 = *(const bf16x8*)(w0 + kk);
        bf16x8 bf1 = *(const bf16x8*)(w1 + kk);
        a00 = __builtin_amdgcn_mfma_f32_16x16x32_bf16(af0, bf0, a00, 0, 0, 0);
        a01 = __builtin_amdgcn_mfma_f32_16x16x32_bf16(af0, bf1, a01, 0, 0, 0);
        a10 = __builtin_amdgcn_mfma_f32_16x16x32_bf16(af1, bf0, a10, 0, 0, 0);
        a11 = __builtin_amdgcn_mfma_f32_16x16x32_bf16(af1, bf1, a11, 0, 0, 0);
    }
    int row = (lane >> 4) * 4;
    size_t base = (size_t)split * (B_ * 128);
    float* g00 = Gpart + base + (size_t)(b0 + row) * 128 + w * 32 + l15;
    float* g10 = Gpart + base + (size_t)(b0 + 16 + row) * 128 + w * 32 + l15;
#pragma unroll
    for (int r = 0; r < 4; ++r) {
        g00[(size_t)r * 128] = a00[r];
        g00[(size_t)r * 128 + 16] = a01[r];
        g10[(size_t)r * 128] = a10[r];
        g10[(size_t)r * 128 + 16] = a11[r];
    }
}

// ---------------------------------------------------------------------------
// per-step small: Ab = sum(Gpart) + rho*AAH*(z-u);  qb = bf16(rho*(z-u) - S^-1*Ab)
__global__ __launch_bounds__(256) void k_small12(const float* Gpart, const float* AAHT,
                                                 const float* Wt, const float* zin,
                                                 const float* uin, const float* lr,
                                                 unsigned short* qb) {
    __shared__ float2 AbS[4][64];
    int t = threadIdx.x;
    int m = t & 63;
    int w = __builtin_amdgcn_readfirstlane(t >> 6);
    int b = blockIdx.x * 4 + w;
    float rho = expf(lr[0]);
    float abR = 0.f, abI = 0.f;
    for (int k = 0; k < 64; ++k) {
        float wr = zin[(b * 2 + 0) * 64 + k] - uin[(b * 2 + 0) * 64 + k];
        float wi = zin[(b * 2 + 1) * 64 + k] - uin[(b * 2 + 1) * 64 + k];
        float2 h = *(const float2*)(AAHT + ((size_t)k * 64 + m) * 2);  // AAH[m][k]
        abR += wr * h.x - wi * h.y;
        abI += wi * h.x + wr * h.y;
    }
    float gR = 0.f, gI = 0.f;
#pragma unroll
    for (int s = 0; s < NSG; ++s) {
        gR += Gpart[(size_t)s * 131072 + (size_t)b * 128 + m];
        gI += Gpart[(size_t)s * 131072 + (size_t)b * 128 + 64 + m];
    }
    abR = gR + rho * abR;
    abI = gI + rho * abI;
    AbS[w][m] = make_float2(abR, abI);
    __syncthreads();
    float tR = 0.f, tI = 0.f;
    for (int k = 0; k < 64; ++k) {
        float2 Wv = *(const float2*)(Wt + ((size_t)k * 64 + m) * 2);   // W[m][k]
        float2 ab = AbS[w][k];
        tR += ab.x * Wv.x - ab.y * Wv.y;
        tI += ab.y * Wv.x + ab.x * Wv.y;
    }
    float wr_m = zin[(b * 2 + 0) * 64 + m] - uin[(b * 2 + 0) * 64 + m];
    float wi_m = zin[(b * 2 + 1) * 64 + m] - uin[(b * 2 + 1) * 64 + m];
    qb[(size_t)b * 128 + m] = f2b(rho * wr_m - tR);
    qb[(size_t)b * 128 + 64 + m] = f2b(rho * wi_m - tI);
}

// ---------------------------------------------------------------------------
// k_H2: x[b][n] = relu(rn_r[b][n] + sum_k qb[b][k]*ATb[n][k]), K=128 (MFMA)
__global__ __launch_bounds__(256) void k_H2(const unsigned short* qb, const unsigned short* ATb,
                                            const float* rn, float* out, unsigned short* xb) {
    int t = threadIdx.x;
    int lane = t & 63;
    int w = t >> 6;
    int l15 = lane & 15;
    int q8 = (lane >> 4) * 8;
    int b0 = blockIdx.y * 16;
    int n0 = blockIdx.x * 1024 + w * 256;
    bf16x8 a[4];
    const unsigned short* qrow = qb + (size_t)(b0 + l15) * 128 + q8;
#pragma unroll
    for (int ks = 0; ks < 4; ++ks) a[ks] = *(const bf16x8*)(qrow + ks * 32);
    int row = (lane >> 4) * 4;
#pragma unroll 2
    for (int nt = 0; nt < 16; ++nt) {
        f32x4 acc = {};
        const unsigned short* bbase = ATb + (size_t)(n0 + nt * 16 + l15) * 128 + q8;
#pragma unroll
        for (int ks = 0; ks < 4; ++ks) {
            bf16x8 bf = *(const bf16x8*)(bbase + ks * 32);
            acc = __builtin_amdgcn_mfma_f32_16x16x32_bf16(a[ks], bf, acc, 0, 0, 0);
        }
        int ncol = n0 + nt * 16 + l15;
        int brow = b0 + row;
#pragma unroll
        for (int r = 0; r < 4; ++r) {
            size_t ridx = (size_t)(brow + r) * 16384 + ncol;   // real row of rn/out
            float v = acc[r] + rn[ridx];
            v = fmaxf(v, 0.f);
            out[ridx] = v;
            xb[(size_t)(brow + r) * 8192 + ncol] = f2b(v);
        }
    }
}

// ---------------------------------------------------------------------------
// k_H3: Axpart[split][b][o] = sum_{k in chunk} xb[b][k]*Abf[o][k]  (MFMA)
__global__ __launch_bounds__(256) void k_H3(const unsigned short* xb, const unsigned short* Abf,
                                            float* Axpart) {
    int t = threadIdx.x;
    int lane = t & 63;
    int w = t >> 6;
    int l15 = lane & 15;
    int q8 = (lane >> 4) * 8;
    int split = blockIdx.x;
    int b0 = blockIdx.y * 32;
    int k0 = split * 512;
    f32x4 a00 = {}, a01 = {}, a10 = {}, a11 = {};
    const unsigned short* x0 = xb + (size_t)(b0 + l15) * 8192 + k0 + q8;
    const unsigned short* x1 = x0 + (size_t)16 * 8192;
    const unsigned short* w0 = Abf + (size_t)(w * 32 + l15) * 8192 + k0 + q8;
    const unsigned short* w1 = w0 + (size_t)16 * 8192;
#pragma unroll 4
    for (int ks = 0; ks < 16; ++ks) {
        int kk = ks * 32;
        bf16x8 af0 = *(const bf16x8*)(x0 + kk);
        bf16x8 af1 = *(const bf16x8*)(x1 + kk);
        bf16x8 bf0 = *(const bf16x8*)(w0 + kk);
        bf16x8 bf1 = *(const bf16x8*)(w1 + kk);
        a00 = __builtin_amdgcn_mfma_f32_16x16x32_bf16(af0, bf0, a00, 0, 0, 0);
        a01 = __builtin_amdgcn_mfma_f32_16x16x32_bf16(af0, bf1, a01, 0, 0, 0);
        a10 = __builtin_amdgcn_mfma_f32_16x16x32_bf16(af1, bf0, a10, 0, 0, 0);
        a11 = __builtin_amdgcn_mfma_f32_16x16x32_bf16(af1, bf1, a11, 0, 0, 0);
    }
    int row = (lane >> 4) * 4;
    size_t base = (size_t)split * (B_ * 128);
    float* g00 = Axpart + base + (size_t)(b0 + row) * 128 + w * 32 + l15;
    float* g10 = Axpart + base + (size_t)(b0 + 16 + row) * 128 + w * 32 + l15;
#pragma unroll
    for (int r = 0; r < 4; ++r) {
        g00[(size_t)r * 128] = a00[r];
        g00[(size_t)r * 128 + 16] = a01[r];
        g10[(size_t)r * 128] = a10[r];
        g10[(size_t)r * 128 + 16] = a11[r];
    }
}

// ---------------------------------------------------------------------------
// per-step epilogue
__global__ __launch_bounds__(128) void k_small3(const float* Axpart, const float* uin,
                                                const float* y, const float* le,
                                                float* z, float* u, float* uout, int last) {
    __shared__ float red[2];
    int b = blockIdx.x, t = threadIdx.x;
    size_t idx = (size_t)b * 128 + t;
    float ax = 0.f;
#pragma unroll
    for (int s = 0; s < NS3; ++s) ax += Axpart[(size_t)s * 131072 + idx];
    float uo = uin[idx], yv = y[idx];
    float v = ax + uo - yv;
    float sq = v * v;
    for (int off = 32; off > 0; off >>= 1) sq += __shfl_down(sq, off, 64);
    if ((t & 63) == 0) red[t >> 6] = sq;
    __syncthreads();
    float tot = red[0] + red[1];
    float eps = expf(le[0]);
    float scale = fminf(1.f, eps / (sqrtf(tot) + 1e-12f));
    float zv = yv + v * scale;
    float un = uo + ax - zv;
    z[idx] = zv;
    u[idx] = un;
    if (last) uout[idx] = un;
}

// ---------------------------------------------------------------------------
extern "C" void kernel_launch(void* const* d_in, const int* in_sizes, int n_in,
                              void* d_out, int out_size, void* d_ws, size_t ws_size,
                              hipStream_t stream) {
    const float* rn  = (const float*)d_in[0];   // (B,2,N)
    const float* y   = (const float*)d_in[1];   // (B,2,M)
    const float* uin = (const float*)d_in[2];   // (B,2,M)
    const float* A   = (const float*)d_in[3];   // (2,M,N)
    const float* lr  = (const float*)d_in[4];   // log_rho
    const float* le  = (const float*)d_in[5];   // log_epsilon

    float* out = (float*)d_out;
    float* ws  = (float*)d_ws;

    float* Gpart  = ws;                          // NSG*B*128      = 4,194,304 f
    float* Axpart = Gpart + (size_t)NSG * 131072;      // NS3*B*128 = 2,097,152 f
    float* S      = Axpart + (size_t)NS3 * 131072;     // 8192
    float* AAHT   = S + 8192;                    // 8192
    float* Wt     = AAHT + 8192;                 // 8192
    float* z      = Wt + 8192;                   // 131072
    float* u      = z + 131072;                  // 131072
    unsigned short* qb  = (unsigned short*)(u + 131072);   // 131072 us
    unsigned short* xb  = qb + 131072;           // B*N          = 8,388,608 us
    unsigned short* WgT = xb + (size_t)B_ * N_;  // 128*16384    = 2,097,152 us
    unsigned short* Abf = WgT + 2097152;         // 2*64*8192    = 1,048,576 us
    unsigned short* ATb = Abf + 1048576;         // 8192*128     = 1,048,576 us
    float* uout = out + (size_t)B_ * 2 * N_;

    k_zero_imag<<<dim3(8, B_), 256, 0, stream>>>(out);
    k_cvtA<<<512, 256, 0, stream>>>(A, Abf);
    k_prep_wg<<<dim3(128, 8), 256, 0, stream>>>(A, WgT);
    k_transpA<<<128, 256, 0, stream>>>(A, ATb);
    k_Sbuild<<<2080, 256, 0, stream>>>(A, lr, S, AAHT);
    k_invert<<<1, 512, 0, stream>>>(S, Wt);
    k_G<<<dim3(NSG, 32), 256, 0, stream>>>(rn, WgT, Gpart);

    for (int step = 0; step < 3; ++step) {
        const float* zp = (step == 0) ? y   : z;
        const float* up = (step == 0) ? uin : u;
        k_small12<<<256, 256, 0, stream>>>(Gpart, AAHT, Wt, zp, up, lr, qb);
        k_H2<<<dim3(8, 64), 256, 0, stream>>>(qb, ATb, rn, out, xb);
        k_H3<<<dim3(NS3, 32), 256, 0, stream>>>(xb, Abf, Axpart);
        k_small3<<<B_, 128, 0, stream>>>(Axpart, up, y, le, z, u, uout, step == 2 ? 1 : 0);
    }
}